// Round 27
// baseline (25.395 us; speedup 1.0000x reference)
//
#include <hip/hip_runtime.h>

// SphericalVectorPool on MI355X — R25 + double-buffered LDS software pipeline.
// R26 post-mortem: every throughput model (VALU/trans/DS/residency) is
// quantitatively excluded; residual ~40% attributed to the per-iteration
// single-buffered LDS RAW chain (write eT/wT -> read -> MFMA) that stalls
// each wave ~200cyc/iter regardless of occupancy. This round: 2 LDS buffers,
// hand-unrolled pipeline READ(i) -> PRELUDE(i+1)->buf[(i+1)&1] -> MFMA(i):
// fragment reads are covered by the next prelude's ~80 VALU instrs in-wave.
// E-gen, K-permuted layout, D-map epilogue identical to R25 (passed, 0.09375).

constexpr int NR    = 16;
constexpr int BATCH = 2;
constexpr int NSRC  = 2048;
constexpr int MOUT  = 2048;

typedef __fp16 h2 __attribute__((ext_vector_type(2)));
typedef _Float16 f16x8 __attribute__((ext_vector_type(8)));
typedef float f32x4 __attribute__((ext_vector_type(4)));

__global__ __launch_bounds__(128, 1) void svp_kernel(
    const float* __restrict__ f,       // [B,N]
    const float* __restrict__ coords,  // [B,N,3]
    const float* __restrict__ outc,    // [B,M,3]
    const float* __restrict__ mu,      // [16]
    const float* __restrict__ rn,      // [16]
    const float* __restrict__ an0,     // [1]
    const float* __restrict__ an1,     // [1]
    float* __restrict__ out)           // [B,M,64]
{
    const int tid  = threadIdx.x;
    const int lane = tid & 63;
    const int w    = tid >> 6;                // wave in block: 0..1
    const int anchor = blockIdx.x;            // 0..4095
    const int b = anchor >> 11;
    const int col = lane & 15;
    const int grp = lane >> 4;

    // [wave][buf][row 0..15=eT,16..19=wT][132 hw] ; 132-hw rows: read stride
    // 264B = 66 dwords -> rotating 2-bank shift, <=2-way conflicts (free).
    __shared__ __align__(16) unsigned short sm[2][2][20][132];
    __shared__ __align__(16) f32x4 red[64];

    const float NL2E = -1.44269504088896340736f;

    const float nm16 = mu[15] * NL2E;
    const float nm14 = mu[13] * NL2E;
    const float nm12 = mu[11] * NL2E;
    const float nm10 = mu[9]  * NL2E;

    const float dl15 = mu[14] - mu[15];
    const float dl13 = mu[12] - mu[13];
    const float dl11 = mu[10] - mu[11];
    const float dl9  = mu[8]  - mu[9];
    const h2 hD15 = __builtin_amdgcn_cvt_pkrtz(dl15, dl15);
    const h2 hD13 = __builtin_amdgcn_cvt_pkrtz(dl13, dl13);
    const h2 hD11 = __builtin_amdgcn_cvt_pkrtz(dl11, dl11);
    const h2 hD9  = __builtin_amdgcn_cvt_pkrtz(dl9,  dl9);

    const h2 C3 = {(__fp16)(-1.0f / 6.0f), (__fp16)(-1.0f / 6.0f)};
    const h2 C2 = {(__fp16)0.5f,  (__fp16)0.5f};
    const h2 C1 = {(__fp16)-1.0f, (__fp16)-1.0f};
    const h2 C0 = {(__fp16)1.0f,  (__fp16)1.0f};

    const float Rx = outc[(size_t)anchor * 3 + 0];
    const float Ry = outc[(size_t)anchor * 3 + 1];
    const float Rz = outc[(size_t)anchor * 3 + 2];

    f32x4 acc = {0.f, 0.f, 0.f, 0.f};

    const float* cb = coords + (size_t)b * NSRC * 3;
    const float* fb = f + (size_t)b * NSRC;

    // K-permuted write position (R25-verified): lane owns local srcs (2t,2t+1)
    const int t = lane & 15;
    const int pos = (t < 8) ? (8 * (t >> 1) + 2 * (t & 1))
                            : (8 * ((t - 8) >> 1) + 4 + 2 * (t & 1));
    const int whw = 32 * (lane >> 4) + pos;
    const int rhw = 8 * grp;

    f16x8 av[4], bv[4];

// compute iteration IT's E/w and write into buffer B (compile-time B)
#define PRELUDE(IT, B)                                                        \
    {                                                                         \
        const int s0 = w * (NSRC / 2) + (IT) * 128 + 2 * lane;                \
        const float2 c0 = *(const float2*)(cb + (size_t)s0 * 3);              \
        const float2 c1 = *(const float2*)(cb + (size_t)s0 * 3 + 2);          \
        const float2 c2 = *(const float2*)(cb + (size_t)s0 * 3 + 4);          \
        const float2 f2 = *(const float2*)(fb + s0);                          \
        const float dx0 = c0.x - Rx, dy0 = c0.y - Ry, dz0 = c1.x - Rz;        \
        const float dx1 = c1.y - Rx, dy1 = c2.x - Ry, dz1 = c2.y - Rz;        \
        const float sq0 = dx0 * dx0 + dy0 * dy0 + dz0 * dz0;                  \
        const float sq1 = dx1 * dx1 + dy1 * dy1 + dz1 * dz1;                  \
        const float ri0 = __builtin_amdgcn_rsqf(sq0);                         \
        const float ri1 = __builtin_amdgcn_rsqf(sq1);                         \
        const float d0 = sq0 * ri0, d1 = sq1 * ri1;                           \
        const float t0 = f2.x * ri0, t1 = f2.y * ri1;                         \
        const h2 dpk = __builtin_amdgcn_cvt_pkrtz(d0, d1);                    \
        h2 ep[16];                                                            \
        ep[15] = __builtin_amdgcn_cvt_pkrtz(                                  \
            __builtin_amdgcn_exp2f(d0 * nm16), __builtin_amdgcn_exp2f(d1 * nm16)); \
        ep[13] = __builtin_amdgcn_cvt_pkrtz(                                  \
            __builtin_amdgcn_exp2f(d0 * nm14), __builtin_amdgcn_exp2f(d1 * nm14)); \
        ep[11] = __builtin_amdgcn_cvt_pkrtz(                                  \
            __builtin_amdgcn_exp2f(d0 * nm12), __builtin_amdgcn_exp2f(d1 * nm12)); \
        ep[9]  = __builtin_amdgcn_cvt_pkrtz(                                  \
            __builtin_amdgcn_exp2f(d0 * nm10), __builtin_amdgcn_exp2f(d1 * nm10)); \
        ep[7] = ep[15] * ep[15];  ep[6] = ep[13] * ep[13];                    \
        ep[5] = ep[11] * ep[11];  ep[4] = ep[9]  * ep[9];                     \
        ep[3] = ep[7]  * ep[7];   ep[2] = ep[5]  * ep[5];                     \
        ep[1] = ep[3]  * ep[3];   ep[0] = ep[1]  * ep[1];                     \
        { h2 x = dpk * hD15; h2 p = C0 + x * (C1 + x * (C2 + x * C3));        \
          ep[14] = ep[15] * p; }                                              \
        { h2 x = dpk * hD13; h2 p = C0 + x * (C1 + x * (C2 + x * C3));        \
          ep[12] = ep[13] * p; }                                              \
        { h2 x = dpk * hD11; h2 p = C0 + x * (C1 + x * (C2 + x * C3));        \
          ep[10] = ep[11] * p; }                                              \
        { h2 x = dpk * hD9;  h2 p = C0 + x * (C1 + x * (C2 + x * C3));        \
          ep[8]  = ep[9]  * p; }                                              \
        _Pragma("unroll")                                                     \
        for (int k = 0; k < 16; ++k)                                          \
            *(unsigned*)&sm[w][B][k][whw] = __builtin_bit_cast(unsigned, ep[k]); \
        *(unsigned*)&sm[w][B][16][whw] =                                      \
            __builtin_bit_cast(unsigned, __builtin_amdgcn_cvt_pkrtz(f2.x, f2.y)); \
        *(unsigned*)&sm[w][B][17][whw] =                                      \
            __builtin_bit_cast(unsigned, __builtin_amdgcn_cvt_pkrtz(t0 * dx0, t1 * dx1)); \
        *(unsigned*)&sm[w][B][18][whw] =                                      \
            __builtin_bit_cast(unsigned, __builtin_amdgcn_cvt_pkrtz(t0 * dy0, t1 * dy1)); \
        *(unsigned*)&sm[w][B][19][whw] =                                      \
            __builtin_bit_cast(unsigned, __builtin_amdgcn_cvt_pkrtz(t0 * dz0, t1 * dz1)); \
    }

// fragment reads from buffer B into av/bv (regs)
#define FREAD(B)                                                              \
    _Pragma("unroll")                                                         \
    for (int c = 0; c < 4; ++c) {                                             \
        av[c] = *(const f16x8*)&sm[w][B][col][32 * c + rhw];                  \
        bv[c] = *(const f16x8*)&sm[w][B][16 + (col & 3)][32 * c + rhw];       \
    }

#define FMMA()                                                                \
    _Pragma("unroll")                                                         \
    for (int c = 0; c < 4; ++c)                                               \
        acc = __builtin_amdgcn_mfma_f32_16x16x32_f16(av[c], bv[c], acc, 0, 0, 0);

    // software pipeline: READ(i) ; PRELUDE(i+1)->other buf ; MFMA(i)
    PRELUDE(0, 0)
    FREAD(0)  PRELUDE(1, 1)  FMMA()
    FREAD(1)  PRELUDE(2, 0)  FMMA()
    FREAD(0)  PRELUDE(3, 1)  FMMA()
    FREAD(1)  PRELUDE(4, 0)  FMMA()
    FREAD(0)  PRELUDE(5, 1)  FMMA()
    FREAD(1)  PRELUDE(6, 0)  FMMA()
    FREAD(0)  PRELUDE(7, 1)  FMMA()
    FREAD(1)  FMMA()

#undef PRELUDE
#undef FREAD
#undef FMMA

    // cross-wave combine
    if (w == 1) red[lane] = acc;
    __syncthreads();
    if (w == 0) {
        acc += red[lane];
        // D[row=4*grp+r][col]: col = component, row = k (m89-verified map)
        if (col < 4) {
            const float4 r4 = *(const float4*)&rn[4 * grp];
            const float an = (col == 0) ? an0[0] : an1[0];
            float4 o;
            o.x = acc[0] * r4.x * an;
            o.y = acc[1] * r4.y * an;
            o.z = acc[2] * r4.z * an;
            o.w = acc[3] * r4.w * an;
            *(float4*)&out[(size_t)anchor * 64 + col * 16 + 4 * grp] = o;
        }
    }
}

extern "C" void kernel_launch(void* const* d_in, const int* in_sizes, int n_in,
                              void* d_out, int out_size, void* d_ws, size_t ws_size,
                              hipStream_t stream) {
    const float* f      = (const float*)d_in[0];
    const float* coords = (const float*)d_in[1];
    const float* outc   = (const float*)d_in[2];
    const float* mu     = (const float*)d_in[3];
    const float* rn     = (const float*)d_in[4];
    const float* an0    = (const float*)d_in[5];
    const float* an1    = (const float*)d_in[6];
    float* out = (float*)d_out;

    const int anchors = BATCH * MOUT;              // 4096 blocks, 2 waves each
    svp_kernel<<<anchors, 128, 0, stream>>>(f, coords, outc, mu, rn, an0, an1, out);
}